// Round 7
// baseline (1031.142 us; speedup 1.0000x reference)
//
#include <hip/hip_runtime.h>

typedef unsigned short u16;
typedef unsigned int u32;
typedef __attribute__((ext_vector_type(8))) short s16x8;
typedef __attribute__((ext_vector_type(4))) float f32x4;

#define B_ 2
#define T_ 2048
#define DM 2048
#define NH 16
#define DH 128
#define SCALE 0.08838834764831845f
#define CAP 50.0f
#define MAGIC_F32 0x3F800000u   // q_norm_w[0]==1.0f as fp32 (probe-confirmed on HW in R4)

__device__ __forceinline__ u16 f2bf(float f){
    u32 u = __float_as_uint(f);
    u32 r = (u + 0x7FFFu + ((u >> 16) & 1u)) >> 16;   // RNE
    return (u16)r;
}
__device__ __forceinline__ float bf2f(u16 h){
    return __uint_as_float(((u32)h) << 16);
}
__device__ __forceinline__ void load8(const void* p, size_t off, int isf32, u16* dst8){
    if (isf32){
        const float* f = (const float*)p + off;
        float4 a = *(const float4*)f;
        float4 b = *(const float4*)(f + 4);
        dst8[0]=f2bf(a.x); dst8[1]=f2bf(a.y); dst8[2]=f2bf(a.z); dst8[3]=f2bf(a.w);
        dst8[4]=f2bf(b.x); dst8[5]=f2bf(b.y); dst8[6]=f2bf(b.z); dst8[7]=f2bf(b.w);
    } else {
        *(int4*)dst8 = *(const int4*)((const u16*)p + off);
    }
}
__device__ __forceinline__ float getf(const void* p, size_t i, int isf32){
    return isf32 ? ((const float*)p)[i] : bf2f(((const u16*)p)[i]);
}

// ---------------- bf16 GEMM, C[M,:] = A[M,K] * B[N,K]^T, C row stride ldc ----------------
// OUT_F32: 0 -> bf16 store (workspace), 1 -> fp32 store (d_out is float32!)
template<int OUT_F32>
__global__ __launch_bounds__(256) void gemm_bt(const void* __restrict__ A,
                                               const void* __restrict__ Bm,
                                               void* __restrict__ Cout,
                                               int M, int N, int K, int ldc,
                                               const u32* __restrict__ magic, int aMode){
    const int f32m = (magic[0] == MAGIC_F32);
    const int aF32 = (aMode == 0) ? 0 : f32m;   // aMode 0: A is workspace bf16
    const int bF32 = f32m;                      // B is always a raw input weight
    __shared__ u16 As[128*72];
    __shared__ u16 Bs[128*72];
    const int n0 = blockIdx.x * 128, m0 = blockIdx.y * 128;
    const int tid = threadIdx.x;
    const int w = tid >> 6, lane = tid & 63, quad = lane >> 4, l15 = lane & 15;
    const int wr = w >> 1, wc = w & 1;
    f32x4 zero = {0.f, 0.f, 0.f, 0.f};
    f32x4 acc[4][4];
    #pragma unroll
    for (int i = 0; i < 4; i++)
        #pragma unroll
        for (int j = 0; j < 4; j++) acc[i][j] = zero;

    for (int k0 = 0; k0 < K; k0 += 64){
        __syncthreads();
        #pragma unroll
        for (int e = 0; e < 4; e++){
            int c = e*256 + tid;
            int r = c >> 3, kc = c & 7;          // r in [0,128), kc in [0,8)
            u16 ta[8], tb[8];
            load8(A,  (size_t)(m0 + r)*K + k0 + kc*8, aF32, ta);
            load8(Bm, (size_t)(n0 + r)*K + k0 + kc*8, bF32, tb);
            *(int4*)(&As[r*72 + kc*8]) = *(int4*)ta;
            *(int4*)(&Bs[r*72 + kc*8]) = *(int4*)tb;
        }
        __syncthreads();
        #pragma unroll
        for (int ks = 0; ks < 2; ks++){
            s16x8 a[4], b[4];
            #pragma unroll
            for (int i = 0; i < 4; i++){
                a[i] = *(const s16x8*)(&As[(wr*64 + i*16 + l15)*72 + ks*32 + quad*8]);
                b[i] = *(const s16x8*)(&Bs[(wc*64 + i*16 + l15)*72 + ks*32 + quad*8]);
            }
            #pragma unroll
            for (int mi = 0; mi < 4; mi++)
                #pragma unroll
                for (int ni = 0; ni < 4; ni++)
                    acc[mi][ni] = __builtin_amdgcn_mfma_f32_16x16x32_bf16(
                        a[mi], b[ni], acc[mi][ni], 0, 0, 0);
        }
    }
    const int row0 = m0 + wr*64 + quad*4;     // C/D: col=lane&15, row=quad*4+reg (m89/m91)
    const int col0 = n0 + wc*64 + l15;
    #pragma unroll
    for (int mi = 0; mi < 4; mi++)
        #pragma unroll
        for (int ni = 0; ni < 4; ni++)
            #pragma unroll
            for (int reg = 0; reg < 4; reg++){
                size_t idx = (size_t)(row0 + mi*16 + reg)*ldc + col0 + ni*16;
                if (OUT_F32) ((float*)Cout)[idx] = acc[mi][ni][reg];
                else         ((u16*)Cout)[idx]  = f2bf(acc[mi][ni][reg]);
            }
}

// ---------------- per-(b,t,h): RMSNorm + RoPE on q,k; write [B,H,T,D] bf16 ----------------
// Reference applies apply_rope AFTER the transpose to (B,NH,T,D); its `n = x.shape[1]` is NH,
// so cos/sin rows are indexed by HEAD h (broadcast over t). Replicated exactly.
__global__ __launch_bounds__(64) void qk_epi(const u16* __restrict__ qkv,
                                             const void* __restrict__ qw,
                                             const void* __restrict__ kw,
                                             const void* __restrict__ cosb,
                                             const void* __restrict__ sinb,
                                             u16* __restrict__ Qg, u16* __restrict__ Kg){
    const int isf32 = (((const u32*)qw)[0] == MAGIC_F32);
    int x = blockIdx.x;
    int h = x & 15, t = (x >> 4) & 2047, b = x >> 15;
    int j = threadIdx.x;             // d = 2j, 2j+1 (RoPE pair)
    const u16* base = qkv + ((size_t)(b*T_ + t))*(3*DM) + h*DH;
    u32 qp = *(const u32*)(base + 2*j);
    u32 kp = *(const u32*)(base + DM + 2*j);
    float q1 = bf2f((u16)qp), q2 = bf2f((u16)(qp >> 16));
    float k1 = bf2f((u16)kp), k2 = bf2f((u16)(kp >> 16));
    float sq = q1*q1 + q2*q2, sk = k1*k1 + k2*k2;
    #pragma unroll
    for (int off = 32; off; off >>= 1){
        sq += __shfl_xor(sq, off);
        sk += __shfl_xor(sk, off);
    }
    float rq = rsqrtf(sq*(1.0f/DH) + 1e-6f);
    float rk = rsqrtf(sk*(1.0f/DH) + 1e-6f);
    float c = getf(cosb, h*64 + j, isf32), s = getf(sinb, h*64 + j, isf32);
    float w1 = getf(qw, 2*j, isf32), w2 = getf(qw, 2*j+1, isf32);
    float u1 = getf(kw, 2*j, isf32), u2 = getf(kw, 2*j+1, isf32);
    q1 *= rq*w1; q2 *= rq*w2;
    k1 *= rk*u1; k2 *= rk*u2;
    u32 qo = (u32)f2bf(q1*c - q2*s) | ((u32)f2bf(q1*s + q2*c) << 16);
    u32 ko = (u32)f2bf(k1*c - k2*s) | ((u32)f2bf(k1*s + k2*c) << 16);
    size_t o = ((size_t)((b*NH + h)*T_ + t))*DH + 2*j;
    *(u32*)(Qg + o) = qo;
    *(u32*)(Kg + o) = ko;
}

// ---------------- V: [b,t,2*DM + h*128+d] (inside qkv) -> Vt [b,h,d,t] bf16 ----------------
__global__ __launch_bounds__(256) void vtrans(const u16* __restrict__ qkv,
                                              u16* __restrict__ Vt){
    __shared__ u16 tile[64*65];
    int tt = blockIdx.x, dt = blockIdx.y, bh = blockIdx.z;
    int b = bh >> 4;
    int tid = threadIdx.x;
    const u16* src = qkv + ((size_t)(b*T_ + tt*64))*(3*DM) + 2*DM + (bh & 15)*DH + dt*64;
    #pragma unroll
    for (int e = 0; e < 2; e++){
        int c = e*256 + tid, r = c >> 3, cc = c & 7;
        int4 v = *(const int4*)(src + (size_t)r*(3*DM) + cc*8);
        u16 us[8]; *(int4*)us = v;
        #pragma unroll
        for (int jj = 0; jj < 8; jj++) tile[(cc*8 + jj)*65 + r] = us[jj];
    }
    __syncthreads();
    u16* dst = Vt + ((size_t)(bh*DH + dt*64))*T_ + tt*64;
    #pragma unroll
    for (int e = 0; e < 2; e++){
        int c = e*256 + tid, rr = c >> 3, tc = c & 7;
        u16 us[8];
        #pragma unroll
        for (int jj = 0; jj < 8; jj++) us[jj] = tile[rr*65 + tc*8 + jj];
        *(int4*)(dst + (size_t)rr*T_ + tc*8) = *(const int4*)us;
    }
}

// ---------------- flash attention, causal, softcap; Q-tile 64 rows ----------------
__global__ __launch_bounds__(256) void attn_kernel(const u16* __restrict__ Qg,
                                                   const u16* __restrict__ Kg,
                                                   const u16* __restrict__ Vt,
                                                   u16* __restrict__ Og){
    __shared__ u16 Qs[64*136];
    __shared__ u16 Ks[64*136];
    __shared__ u16 Vs[128*72];
    __shared__ u16 Sb[4*16*72];
    const int bh = blockIdx.y;
    const int b = bh >> 4, h = bh & 15;
    const int qt = gridDim.x - 1 - blockIdx.x;
    const int q0 = qt * 64;
    const int tid = threadIdx.x, w = tid >> 6, lane = tid & 63;
    const int quad = lane >> 4, l15 = lane & 15;
    const u16* Qb = Qg + (size_t)bh * T_ * DH;
    const u16* Kb = Kg + (size_t)bh * T_ * DH;

    #pragma unroll
    for (int e = 0; e < 4; e++){
        int c = e*256 + tid, r = c >> 4, cc = c & 15;
        *(int4*)(&Qs[r*136 + cc*8]) = *(const int4*)(Qb + (size_t)(q0 + r)*DH + cc*8);
    }

    float m_i[4], l_i[4];
    f32x4 zero = {0.f,0.f,0.f,0.f};
    f32x4 acc[8];
    #pragma unroll
    for (int i = 0; i < 4; i++){ m_i[i] = -INFINITY; l_i[i] = 0.f; }
    #pragma unroll
    for (int i = 0; i < 8; i++) acc[i] = zero;

    for (int kt = 0; kt <= qt; kt++){
        __syncthreads();
        #pragma unroll
        for (int e = 0; e < 4; e++){
            int c = e*256 + tid, r = c >> 4, cc = c & 15;
            *(int4*)(&Ks[r*136 + cc*8]) = *(const int4*)(Kb + (size_t)(kt*64 + r)*DH + cc*8);
        }
        const u16* Vb = Vt + (size_t)bh*DH*T_ + kt*64;
        #pragma unroll
        for (int e = 0; e < 4; e++){
            int c = e*256 + tid, r = c >> 3, cc = c & 7;
            *(int4*)(&Vs[r*72 + cc*8]) = *(const int4*)(Vb + (size_t)r*T_ + cc*8);
        }
        __syncthreads();

        s16x8 afr[4];
        #pragma unroll
        for (int ks = 0; ks < 4; ks++)
            afr[ks] = *(const s16x8*)(&Qs[(w*16 + l15)*136 + ks*32 + quad*8]);
        f32x4 sfr[4];
        #pragma unroll
        for (int ni = 0; ni < 4; ni++){
            sfr[ni] = zero;
            #pragma unroll
            for (int ks = 0; ks < 4; ks++){
                s16x8 bfr = *(const s16x8*)(&Ks[(ni*16 + l15)*136 + ks*32 + quad*8]);
                sfr[ni] = __builtin_amdgcn_mfma_f32_16x16x32_bf16(afr[ks], bfr, sfr[ni], 0,0,0);
            }
        }

        const bool diag = (kt == qt);
        float sv[4][4];
        float rmax[4] = {-INFINITY, -INFINITY, -INFINITY, -INFINITY};
        #pragma unroll
        for (int ni = 0; ni < 4; ni++)
            #pragma unroll
            for (int reg = 0; reg < 4; reg++){
                float xv = sfr[ni][reg] * SCALE;
                float e2 = __expf(xv * (2.0f/CAP));
                xv = CAP * ((e2 - 1.0f) / (e2 + 1.0f));
                if (diag && (kt*64 + ni*16 + l15 > q0 + w*16 + quad*4 + reg))
                    xv = -INFINITY;
                sv[ni][reg] = xv;
                rmax[reg] = fmaxf(rmax[reg], xv);
            }
        #pragma unroll
        for (int off = 1; off < 16; off <<= 1)
            #pragma unroll
            for (int reg = 0; reg < 4; reg++)
                rmax[reg] = fmaxf(rmax[reg], __shfl_xor(rmax[reg], off));

        float alpha[4], ps[4];
        #pragma unroll
        for (int reg = 0; reg < 4; reg++){
            float mn = fmaxf(m_i[reg], rmax[reg]);
            alpha[reg] = __expf(m_i[reg] - mn);
            m_i[reg] = mn;
            ps[reg] = 0.f;
        }
        #pragma unroll
        for (int ni = 0; ni < 4; ni++)
            #pragma unroll
            for (int reg = 0; reg < 4; reg++){
                float p = __expf(sv[ni][reg] - m_i[reg]);
                ps[reg] += p;
                Sb[w*1152 + (quad*4 + reg)*72 + ni*16 + l15] = f2bf(p);
            }
        #pragma unroll
        for (int off = 1; off < 16; off <<= 1)
            #pragma unroll
            for (int reg = 0; reg < 4; reg++)
                ps[reg] += __shfl_xor(ps[reg], off);
        #pragma unroll
        for (int reg = 0; reg < 4; reg++)
            l_i[reg] = l_i[reg]*alpha[reg] + ps[reg];
        #pragma unroll
        for (int no = 0; no < 8; no++)
            #pragma unroll
            for (int reg = 0; reg < 4; reg++)
                acc[no][reg] *= alpha[reg];

        s16x8 pa[2];
        #pragma unroll
        for (int kk = 0; kk < 2; kk++)
            pa[kk] = *(const s16x8*)(&Sb[w*1152 + l15*72 + kk*32 + quad*8]);
        #pragma unroll
        for (int no = 0; no < 8; no++)
            #pragma unroll
            for (int kk = 0; kk < 2; kk++){
                s16x8 vb = *(const s16x8*)(&Vs[(no*16 + l15)*72 + kk*32 + quad*8]);
                acc[no] = __builtin_amdgcn_mfma_f32_16x16x32_bf16(pa[kk], vb, acc[no], 0,0,0);
            }
    }

    float inv[4];
    #pragma unroll
    for (int reg = 0; reg < 4; reg++) inv[reg] = 1.0f / l_i[reg];
    u16* Ob = Og + ((size_t)(b*T_ + q0 + w*16 + quad*4))*DM + h*DH + l15;
    #pragma unroll
    for (int no = 0; no < 8; no++)
        #pragma unroll
        for (int reg = 0; reg < 4; reg++)
            Ob[(size_t)reg*DM + no*16] = f2bf(acc[no][reg] * inv[reg]);
}

extern "C" void kernel_launch(void* const* d_in, const int* in_sizes, int n_in,
                              void* d_out, int out_size, void* d_ws, size_t ws_size,
                              hipStream_t stream) {
    const void* x   = d_in[0];
    const void* wq  = d_in[1];
    const void* wk  = d_in[2];
    const void* wv  = d_in[3];
    const void* wo  = d_in[4];
    const void* qnw = d_in[5];
    const void* knw = d_in[6];
    const void* rc  = d_in[7];
    const void* rs  = d_in[8];
    const u32* magic = (const u32*)qnw;   // fp32 storage confirmed on HW (R4 probe)

    const size_t NTOK = (size_t)B_ * T_;           // 4096
    u16* wsp = (u16*)d_ws;
    u16* qkv = wsp;                                // 25,165,824 elems
    u16* Qg  = qkv + NTOK*(size_t)(3*DM);          //  8,388,608
    u16* Kg  = Qg + NTOK*DM;
    u16* Vt  = Kg + NTOK*DM;
    u16* Og  = Vt + NTOK*DM;
    const size_t need = (size_t)(Og + NTOK*DM - wsp) * sizeof(u16);
    if (ws_size < need) return;   // ~117 MB

    gemm_bt<0><<<dim3(16, 32), 256, 0, stream>>>(x, wq, qkv,        4096, 2048, 2048, 3*DM, magic, 1);
    gemm_bt<0><<<dim3(16, 32), 256, 0, stream>>>(x, wk, qkv + DM,   4096, 2048, 2048, 3*DM, magic, 1);
    gemm_bt<0><<<dim3(16, 32), 256, 0, stream>>>(x, wv, qkv + 2*DM, 4096, 2048, 2048, 3*DM, magic, 1);
    qk_epi<<<65536, 64, 0, stream>>>(qkv, qnw, knw, rc, rs, Qg, Kg);
    vtrans<<<dim3(32, 2, 32), 256, 0, stream>>>(qkv, Vt);
    attn_kernel<<<dim3(32, 32), 256, 0, stream>>>(Qg, Kg, Vt, Og);
    // d_out is FLOAT32 (reference output dtype) — fp32 store
    gemm_bt<1><<<dim3(16, 32), 256, 0, stream>>>(Og, wo, d_out, 4096, 2048, 2048, 2048, magic, 0);
}

// Round 8
// 649.342 us; speedup vs baseline: 1.5880x; 1.5880x over previous
//
#include <hip/hip_runtime.h>

typedef unsigned short u16;
typedef unsigned int u32;
typedef __attribute__((ext_vector_type(8))) short s16x8;
typedef __attribute__((ext_vector_type(4))) float f32x4;

#define B_ 2
#define T_ 2048
#define DM 2048
#define NH 16
#define DH 128
#define SCALE 0.08838834764831845f
#define CAP 50.0f
#define MAGIC_F32 0x3F800000u

__device__ __forceinline__ u16 f2bf(float f){
    u32 u = __float_as_uint(f);
    u32 r = (u + 0x7FFFu + ((u >> 16) & 1u)) >> 16;   // RNE
    return (u16)r;
}
__device__ __forceinline__ float bf2f(u16 h){
    return __uint_as_float(((u32)h) << 16);
}
__device__ __forceinline__ float getf(const void* p, size_t i, int isf32){
    return isf32 ? ((const float*)p)[i] : bf2f(((const u16*)p)[i]);
}

// ---------------- fp32 -> bf16 bulk convert, 8 elems/thread ----------------
__global__ __launch_bounds__(256) void cvt(const float* __restrict__ src,
                                           u16* __restrict__ dst, int n8){
    int i = blockIdx.x * 256 + threadIdx.x;
    if (i < n8){
        const float* f = src + (size_t)i * 8;
        float4 a = *(const float4*)f;
        float4 b = *(const float4*)(f + 4);
        u16 o[8] = {f2bf(a.x), f2bf(a.y), f2bf(a.z), f2bf(a.w),
                    f2bf(b.x), f2bf(b.y), f2bf(b.z), f2bf(b.w)};
        *(int4*)(dst + (size_t)i * 8) = *(int4*)o;
    }
}

// ---------------- pure-bf16 GEMM, C[M,:] = A[M,K] * B[N,K]^T ----------------
// 128x128 tile, 4 waves, BK=64, LDS rows padded to 72 (R1/R7-proven structure).
template<int OUT_F32>
__global__ __launch_bounds__(256) void gemm_bt(const u16* __restrict__ A,
                                               const u16* __restrict__ Bm,
                                               void* __restrict__ Cout,
                                               int M, int N, int K, int ldc){
    __shared__ u16 As[128*72];
    __shared__ u16 Bs[128*72];
    const int n0 = blockIdx.x * 128, m0 = blockIdx.y * 128;
    const int tid = threadIdx.x;
    const int w = tid >> 6, lane = tid & 63, quad = lane >> 4, l15 = lane & 15;
    const int wr = w >> 1, wc = w & 1;
    f32x4 zero = {0.f, 0.f, 0.f, 0.f};
    f32x4 acc[4][4];
    #pragma unroll
    for (int i = 0; i < 4; i++)
        #pragma unroll
        for (int j = 0; j < 4; j++) acc[i][j] = zero;

    for (int k0 = 0; k0 < K; k0 += 64){
        __syncthreads();
        #pragma unroll
        for (int e = 0; e < 4; e++){
            int c = e*256 + tid;
            int r = c >> 3, kc = c & 7;
            *(int4*)(&As[r*72 + kc*8]) = *(const int4*)(A  + (size_t)(m0 + r)*K + k0 + kc*8);
            *(int4*)(&Bs[r*72 + kc*8]) = *(const int4*)(Bm + (size_t)(n0 + r)*K + k0 + kc*8);
        }
        __syncthreads();
        #pragma unroll
        for (int ks = 0; ks < 2; ks++){
            s16x8 a[4], b[4];
            #pragma unroll
            for (int i = 0; i < 4; i++){
                a[i] = *(const s16x8*)(&As[(wr*64 + i*16 + l15)*72 + ks*32 + quad*8]);
                b[i] = *(const s16x8*)(&Bs[(wc*64 + i*16 + l15)*72 + ks*32 + quad*8]);
            }
            #pragma unroll
            for (int mi = 0; mi < 4; mi++)
                #pragma unroll
                for (int ni = 0; ni < 4; ni++)
                    acc[mi][ni] = __builtin_amdgcn_mfma_f32_16x16x32_bf16(
                        a[mi], b[ni], acc[mi][ni], 0, 0, 0);
        }
    }
    const int row0 = m0 + wr*64 + quad*4;     // C/D: col=lane&15, row=quad*4+reg
    const int col0 = n0 + wc*64 + l15;
    #pragma unroll
    for (int mi = 0; mi < 4; mi++)
        #pragma unroll
        for (int ni = 0; ni < 4; ni++)
            #pragma unroll
            for (int reg = 0; reg < 4; reg++){
                size_t idx = (size_t)(row0 + mi*16 + reg)*ldc + col0 + ni*16;
                if (OUT_F32) ((float*)Cout)[idx] = acc[mi][ni][reg];
                else         ((u16*)Cout)[idx]  = f2bf(acc[mi][ni][reg]);
            }
}

// ---------------- RMSNorm + RoPE (head-indexed, per reference quirk) ----------------
// 256 threads = 4 groups of 64; each group handles one (b,t,h).
__global__ __launch_bounds__(256) void qk_epi(const u16* __restrict__ qkv,
                                              const void* __restrict__ qw,
                                              const void* __restrict__ kw,
                                              const void* __restrict__ cosb,
                                              const void* __restrict__ sinb,
                                              u16* __restrict__ Qg, u16* __restrict__ Kg){
    const int isf32 = (((const u32*)qw)[0] == MAGIC_F32);
    int g = blockIdx.x * 4 + (threadIdx.x >> 6);
    int h = g & 15, t = (g >> 4) & 2047, b = g >> 15;
    int j = threadIdx.x & 63;        // d = 2j, 2j+1
    const u16* base = qkv + ((size_t)(b*T_ + t))*(3*DM) + h*DH;
    u32 qp = *(const u32*)(base + 2*j);
    u32 kp = *(const u32*)(base + DM + 2*j);
    float q1 = bf2f((u16)qp), q2 = bf2f((u16)(qp >> 16));
    float k1 = bf2f((u16)kp), k2 = bf2f((u16)(kp >> 16));
    float sq = q1*q1 + q2*q2, sk = k1*k1 + k2*k2;
    #pragma unroll
    for (int off = 32; off; off >>= 1){
        sq += __shfl_xor(sq, off);
        sk += __shfl_xor(sk, off);
    }
    float rq = rsqrtf(sq*(1.0f/DH) + 1e-6f);
    float rk = rsqrtf(sk*(1.0f/DH) + 1e-6f);
    float c = getf(cosb, h*64 + j, isf32), s = getf(sinb, h*64 + j, isf32);
    float w1 = getf(qw, 2*j, isf32), w2 = getf(qw, 2*j+1, isf32);
    float u1 = getf(kw, 2*j, isf32), u2 = getf(kw, 2*j+1, isf32);
    q1 *= rq*w1; q2 *= rq*w2;
    k1 *= rk*u1; k2 *= rk*u2;
    u32 qo = (u32)f2bf(q1*c - q2*s) | ((u32)f2bf(q1*s + q2*c) << 16);
    u32 ko = (u32)f2bf(k1*c - k2*s) | ((u32)f2bf(k1*s + k2*c) << 16);
    size_t o = ((size_t)((b*NH + h)*T_ + t))*DH + 2*j;
    *(u32*)(Qg + o) = qo;
    *(u32*)(Kg + o) = ko;
}

// ---------------- V: qkv[b,t,2*DM + h*DH + d] -> Vt [b,h,d,t] ----------------
__global__ __launch_bounds__(256) void vtrans(const u16* __restrict__ qkv,
                                              u16* __restrict__ Vt){
    __shared__ u16 tile[64*65];
    int tt = blockIdx.x, dt = blockIdx.y, bh = blockIdx.z;
    int b = bh >> 4;
    int tid = threadIdx.x;
    const u16* src = qkv + ((size_t)(b*T_ + tt*64))*(3*DM) + 2*DM + (bh & 15)*DH + dt*64;
    #pragma unroll
    for (int e = 0; e < 2; e++){
        int c = e*256 + tid, r = c >> 3, cc = c & 7;
        int4 v = *(const int4*)(src + (size_t)r*(3*DM) + cc*8);
        u16 us[8]; *(int4*)us = v;
        #pragma unroll
        for (int jj = 0; jj < 8; jj++) tile[(cc*8 + jj)*65 + r] = us[jj];
    }
    __syncthreads();
    u16* dst = Vt + ((size_t)(bh*DH + dt*64))*T_ + tt*64;
    #pragma unroll
    for (int e = 0; e < 2; e++){
        int c = e*256 + tid, rr = c >> 3, tc = c & 7;
        u16 us[8];
        #pragma unroll
        for (int jj = 0; jj < 8; jj++) us[jj] = tile[rr*65 + tc*8 + jj];
        *(int4*)(dst + (size_t)rr*T_ + tc*8) = *(const int4*)us;
    }
}

// ---------------- flash attention, causal, softcap; reg-prefetch K/V dbuf ----------------
__global__ __launch_bounds__(256) void attn_kernel(const u16* __restrict__ Qg,
                                                   const u16* __restrict__ Kg,
                                                   const u16* __restrict__ Vt,
                                                   u16* __restrict__ Og){
    __shared__ u16 Qs[64*136];
    __shared__ u16 Ks[64*136];
    __shared__ u16 Vs[128*72];
    __shared__ u16 Sb[4*16*72];
    const int bh = blockIdx.y;
    const int b = bh >> 4, h = bh & 15;
    const int qt = gridDim.x - 1 - blockIdx.x;   // heavy tiles first
    const int q0 = qt * 64;
    const int tid = threadIdx.x, w = tid >> 6, lane = tid & 63;
    const int quad = lane >> 4, l15 = lane & 15;
    const u16* Qb = Qg + (size_t)bh * T_ * DH;
    const u16* Kb = Kg + (size_t)bh * T_ * DH;
    const u16* Vbase = Vt + (size_t)bh * DH * T_;

    #pragma unroll
    for (int e = 0; e < 4; e++){
        int c = e*256 + tid, r = c >> 4, cc = c & 15;
        *(int4*)(&Qs[r*136 + cc*8]) = *(const int4*)(Qb + (size_t)(q0 + r)*DH + cc*8);
    }

    // prefetch registers for K (64x128) and V (128x64): 4 int4 each
    int4 kreg[4], vreg[4];
    {
        #pragma unroll
        for (int e = 0; e < 4; e++){
            int c = e*256 + tid, r = c >> 4, cc = c & 15;
            kreg[e] = *(const int4*)(Kb + (size_t)r*DH + cc*8);          // kt = 0
        }
        #pragma unroll
        for (int e = 0; e < 4; e++){
            int c = e*256 + tid, r = c >> 3, cc = c & 7;
            vreg[e] = *(const int4*)(Vbase + (size_t)r*T_ + cc*8);       // kt = 0
        }
    }

    float m_i[4], l_i[4];
    f32x4 zero = {0.f,0.f,0.f,0.f};
    f32x4 acc[8];
    #pragma unroll
    for (int i = 0; i < 4; i++){ m_i[i] = -INFINITY; l_i[i] = 0.f; }
    #pragma unroll
    for (int i = 0; i < 8; i++) acc[i] = zero;

    for (int kt = 0; kt <= qt; kt++){
        __syncthreads();                 // prior-iter LDS readers done
        #pragma unroll
        for (int e = 0; e < 4; e++){
            int c = e*256 + tid, r = c >> 4, cc = c & 15;
            *(int4*)(&Ks[r*136 + cc*8]) = kreg[e];
        }
        #pragma unroll
        for (int e = 0; e < 4; e++){
            int c = e*256 + tid, r = c >> 3, cc = c & 7;
            *(int4*)(&Vs[r*72 + cc*8]) = vreg[e];
        }
        __syncthreads();                 // tile kt visible

        if (kt < qt){                    // issue next-tile loads; land during compute
            #pragma unroll
            for (int e = 0; e < 4; e++){
                int c = e*256 + tid, r = c >> 4, cc = c & 15;
                kreg[e] = *(const int4*)(Kb + (size_t)((kt+1)*64 + r)*DH + cc*8);
            }
            const u16* Vb = Vbase + (kt+1)*64;
            #pragma unroll
            for (int e = 0; e < 4; e++){
                int c = e*256 + tid, r = c >> 3, cc = c & 7;
                vreg[e] = *(const int4*)(Vb + (size_t)r*T_ + cc*8);
            }
        }

        // ---- S = Q K^T
        s16x8 afr[4];
        #pragma unroll
        for (int ks = 0; ks < 4; ks++)
            afr[ks] = *(const s16x8*)(&Qs[(w*16 + l15)*136 + ks*32 + quad*8]);
        f32x4 sfr[4];
        #pragma unroll
        for (int ni = 0; ni < 4; ni++){
            sfr[ni] = zero;
            #pragma unroll
            for (int ks = 0; ks < 4; ks++){
                s16x8 bfr = *(const s16x8*)(&Ks[(ni*16 + l15)*136 + ks*32 + quad*8]);
                sfr[ni] = __builtin_amdgcn_mfma_f32_16x16x32_bf16(afr[ks], bfr, sfr[ni], 0,0,0);
            }
        }

        // ---- softcap + mask + online softmax
        const bool diag = (kt == qt);
        float sv[4][4];
        float rmax[4] = {-INFINITY, -INFINITY, -INFINITY, -INFINITY};
        #pragma unroll
        for (int ni = 0; ni < 4; ni++)
            #pragma unroll
            for (int reg = 0; reg < 4; reg++){
                float xv = sfr[ni][reg] * SCALE;
                float e2 = __expf(xv * (2.0f/CAP));
                xv = CAP * ((e2 - 1.0f) / (e2 + 1.0f));
                if (diag && (kt*64 + ni*16 + l15 > q0 + w*16 + quad*4 + reg))
                    xv = -INFINITY;
                sv[ni][reg] = xv;
                rmax[reg] = fmaxf(rmax[reg], xv);
            }
        #pragma unroll
        for (int off = 1; off < 16; off <<= 1)
            #pragma unroll
            for (int reg = 0; reg < 4; reg++)
                rmax[reg] = fmaxf(rmax[reg], __shfl_xor(rmax[reg], off));

        float alpha[4], ps[4];
        #pragma unroll
        for (int reg = 0; reg < 4; reg++){
            float mn = fmaxf(m_i[reg], rmax[reg]);
            alpha[reg] = __expf(m_i[reg] - mn);
            m_i[reg] = mn;
            ps[reg] = 0.f;
        }
        #pragma unroll
        for (int ni = 0; ni < 4; ni++)
            #pragma unroll
            for (int reg = 0; reg < 4; reg++){
                float p = __expf(sv[ni][reg] - m_i[reg]);
                ps[reg] += p;
                Sb[w*1152 + (quad*4 + reg)*72 + ni*16 + l15] = f2bf(p);
            }
        #pragma unroll
        for (int off = 1; off < 16; off <<= 1)
            #pragma unroll
            for (int reg = 0; reg < 4; reg++)
                ps[reg] += __shfl_xor(ps[reg], off);
        #pragma unroll
        for (int reg = 0; reg < 4; reg++)
            l_i[reg] = l_i[reg]*alpha[reg] + ps[reg];
        #pragma unroll
        for (int no = 0; no < 8; no++)
            #pragma unroll
            for (int reg = 0; reg < 4; reg++)
                acc[no][reg] *= alpha[reg];

        // ---- O += P V
        s16x8 pa[2];
        #pragma unroll
        for (int kk = 0; kk < 2; kk++)
            pa[kk] = *(const s16x8*)(&Sb[w*1152 + l15*72 + kk*32 + quad*8]);
        #pragma unroll
        for (int no = 0; no < 8; no++)
            #pragma unroll
            for (int kk = 0; kk < 2; kk++){
                s16x8 vb = *(const s16x8*)(&Vs[(no*16 + l15)*72 + kk*32 + quad*8]);
                acc[no] = __builtin_amdgcn_mfma_f32_16x16x32_bf16(pa[kk], vb, acc[no], 0,0,0);
            }
    }

    float inv[4];
    #pragma unroll
    for (int reg = 0; reg < 4; reg++) inv[reg] = 1.0f / l_i[reg];
    u16* Ob = Og + ((size_t)(b*T_ + q0 + w*16 + quad*4))*DM + h*DH + l15;
    #pragma unroll
    for (int no = 0; no < 8; no++)
        #pragma unroll
        for (int reg = 0; reg < 4; reg++)
            Ob[(size_t)reg*DM + no*16] = f2bf(acc[no][reg] * inv[reg]);
}

extern "C" void kernel_launch(void* const* d_in, const int* in_sizes, int n_in,
                              void* d_out, int out_size, void* d_ws, size_t ws_size,
                              hipStream_t stream) {
    const float* x  = (const float*)d_in[0];
    const float* wq = (const float*)d_in[1];
    const float* wk = (const float*)d_in[2];
    const float* wv = (const float*)d_in[3];
    const float* wo = (const float*)d_in[4];
    const void* qnw = d_in[5];
    const void* knw = d_in[6];
    const void* rc  = d_in[7];
    const void* rs  = d_in[8];

    const size_t NTOK = (size_t)B_ * T_;            // 4096
    u16* wsp  = (u16*)d_ws;
    u16* xb   = wsp;                                //  8,388,608   (Og aliases later)
    u16* wcat = xb + NTOK*DM;                       // 12,582,912   (Vt aliases first 8.4M later)
    u16* wob  = wcat + (size_t)3*DM*DM;             //  4,194,304
    u16* qkv  = wob + (size_t)DM*DM;                // 25,165,824
    u16* Qg   = qkv + NTOK*(size_t)(3*DM);          //  8,388,608
    u16* Kg   = Qg + NTOK*DM;
    u16* Vt   = wcat;                               // alias: wcat dead after GEMM1
    u16* Og   = xb;                                 // alias: xb dead after GEMM1
    const size_t need = (size_t)(Kg + NTOK*DM - wsp) * sizeof(u16);
    if (ws_size < need) return;   // 134 MB (<= 151 MB verified in R0/R1)

    cvt<<<4096, 256, 0, stream>>>(x,  xb,   1048576);
    cvt<<<2048, 256, 0, stream>>>(wq, wcat,           524288);
    cvt<<<2048, 256, 0, stream>>>(wk, wcat + 4194304, 524288);
    cvt<<<2048, 256, 0, stream>>>(wv, wcat + 8388608, 524288);
    cvt<<<2048, 256, 0, stream>>>(wo, wob,  524288);

    // fused QKV projection: C[m, 3*DM] interleaved q|k|v rows via N=6144, ldc=6144
    gemm_bt<0><<<dim3(48, 32), 256, 0, stream>>>(xb, wcat, qkv, 4096, 6144, 2048, 3*DM);
    qk_epi<<<16384, 256, 0, stream>>>(qkv, qnw, knw, rc, rs, Qg, Kg);
    vtrans<<<dim3(32, 2, 32), 256, 0, stream>>>(qkv, Vt);
    attn_kernel<<<dim3(32, 32), 256, 0, stream>>>(Qg, Kg, Vt, Og);
    gemm_bt<1><<<dim3(16, 32), 256, 0, stream>>>(Og, wob, d_out, 4096, 2048, 2048, 2048);
}